// Round 1
// baseline (536.131 us; speedup 1.0000x reference)
//
#include <hip/hip_runtime.h>
#include <hip/hip_bf16.h>

// Problem constants
#define B_    4096
#define F_    32
#define V_    50000
#define E_    64
#define D1_   256
#define DD_   16
#define L2N_  128
#define K_EMB   2048   // F*E
#define K_INNER 1024   // F*F
#define K_OUTER 4096   // E*E
#define K_TOT   7168
#define K_X     3072   // stored X width (emb|inner); outer synthesized from s

// ws layout (floats) — needs 16,777,216 floats = 64 MiB
//  X  : [B][3072]   @ 0
//  WT : [7168][256] @ 12,582,912
//  S  : [B][64]     @ 14,417,920
//  L1 : [B][256]    @ 14,680,064
//  H1 : [B][256]    @ 15,728,640

// ---------------- K0: build WT = [Wz;Wpi;Wpo]^T (k-major, d contiguous) ---
__global__ __launch_bounds__(256) void prep_wt(
    const float* __restrict__ Wz, const float* __restrict__ Wpi,
    const float* __restrict__ Wpo, float* __restrict__ WT) {
  int k = blockIdx.x;      // 0..7167
  int d = threadIdx.x;     // 0..255
  float v;
  if (k < K_EMB)                 v = Wz [(size_t)d * K_EMB   + k];
  else if (k < K_EMB + K_INNER)  v = Wpi[(size_t)d * K_INNER + (k - K_EMB)];
  else                           v = Wpo[(size_t)d * K_OUTER + (k - K_EMB - K_INNER)];
  WT[(size_t)k * D1_ + d] = v;
}

// ---------------- K1: gather emb, compute s and gram(inner) --------------
__global__ __launch_bounds__(256) void gather_feats(
    const int* __restrict__ sparse, const float* __restrict__ tables,
    float* __restrict__ X, float* __restrict__ S) {
  int b = blockIdx.x;
  int t = threadIdx.x;
  __shared__ float emb[F_ * 65];   // stride 65 kills bank conflicts
  const int* sp = sparse + b * F_;

  int e  = t & 63;
  int f0 = t >> 6;                 // 0..3
#pragma unroll
  for (int r = 0; r < 8; ++r) {
    int f = f0 + r * 4;
    int idx = sp[f];
    float v = tables[((size_t)f * V_ + idx) * E_ + e];
    emb[f * 65 + e] = v;
    X[(size_t)b * K_X + f * E_ + e] = v;
  }
  __syncthreads();

  if (t < E_) {                    // s = emb.sum(axis=f)
    float acc = 0.f;
#pragma unroll
    for (int f = 0; f < F_; ++f) acc += emb[f * 65 + t];
    S[(size_t)b * E_ + t] = acc;
  }

#pragma unroll
  for (int r = 0; r < 4; ++r) {    // inner[i][j] = emb[i,:]·emb[j,:]
    int p = t + 256 * r;
    int i = p >> 5, j = p & 31;
    const float* ei = emb + i * 65;
    const float* ej = emb + j * 65;
    float acc = 0.f;
#pragma unroll
    for (int q = 0; q < E_; ++q) acc += ei[q] * ej[q];
    X[(size_t)b * K_X + K_EMB + p] = acc;
  }
}

// ---------------- K2: L1 = X' @ WT + (bz+bpi+bpo+B1) ---------------------
#define BM 64
#define BN 64
#define BK 32
__global__ __launch_bounds__(256) void gemm_l1(
    const float* __restrict__ X, const float* __restrict__ WT,
    const float* __restrict__ S,
    const float* __restrict__ bz, const float* __restrict__ bpi,
    const float* __restrict__ bpo, const float* __restrict__ B1v,
    float* __restrict__ L1) {
  __shared__ float Xs[BK][BM];
  __shared__ float Ws[BK][BN];
  __shared__ float Ss[64 * 65];    // s rows for 64 batch rows, stride 65

  int bRow = blockIdx.x * BM;
  int n0   = blockIdx.y * BN;
  int tid  = threadIdx.x;

  // stage s block (contiguous 4096 floats -> padded LDS)
#pragma unroll
  for (int r = 0; r < 4; ++r) {
    int idx = r * 1024 + tid * 4;
    float4 v = *(const float4*)&S[(size_t)bRow * E_ + idx];
    int m = idx >> 6, ee = idx & 63;
    Ss[m * 65 + ee + 0] = v.x; Ss[m * 65 + ee + 1] = v.y;
    Ss[m * 65 + ee + 2] = v.z; Ss[m * 65 + ee + 3] = v.w;
  }

  float acc[4][4] = {};
  int tm = tid >> 4, tn = tid & 15;
  int mBase = tm * 4, nBase = tn * 4;
  int sm  = tid >> 3;        // staging m (0..31, +32)
  int sk4 = (tid & 7) * 4;   // staging kk base

  for (int kt = 0; kt < K_TOT / BK; ++kt) {
    int k0 = kt * BK;
    __syncthreads();
    if (k0 < K_X) {          // emb|inner region: load from global X
#pragma unroll
      for (int h = 0; h < 2; ++h) {
        int m = sm + h * 32;
        float4 v = *(const float4*)&X[(size_t)(bRow + m) * K_X + k0 + sk4];
        Xs[sk4 + 0][m] = v.x; Xs[sk4 + 1][m] = v.y;
        Xs[sk4 + 2][m] = v.z; Xs[sk4 + 3][m] = v.w;
      }
    } else {                 // outer region: synthesize s_i * s_j
      int p0 = k0 - K_X;
      int i  = p0 >> 6;
      int jb = p0 & 63;
#pragma unroll
      for (int h = 0; h < 2; ++h) {
        int m = sm + h * 32;
        float si = Ss[m * 65 + i];
#pragma unroll
        for (int q = 0; q < 4; ++q)
          Xs[sk4 + q][m] = si * Ss[m * 65 + jb + sk4 + q];
      }
    }
    {                        // W tile
      int n4 = (tid & 15) * 4;
      int kk = tid >> 4;
#pragma unroll
      for (int h = 0; h < 2; ++h) {
        int kkh = kk + h * 16;
        float4 v = *(const float4*)&WT[(size_t)(k0 + kkh) * D1_ + n0 + n4];
        *(float4*)&Ws[kkh][n4] = v;
      }
    }
    __syncthreads();
#pragma unroll
    for (int kk = 0; kk < BK; ++kk) {
      float4 xv = *(const float4*)&Xs[kk][mBase];
      float4 wv = *(const float4*)&Ws[kk][nBase];
      float xa[4] = {xv.x, xv.y, xv.z, xv.w};
      float wa[4] = {wv.x, wv.y, wv.z, wv.w};
#pragma unroll
      for (int im = 0; im < 4; ++im)
#pragma unroll
        for (int in = 0; in < 4; ++in)
          acc[im][in] += xa[im] * wa[in];
    }
  }

#pragma unroll
  for (int in = 0; in < 4; ++in) {
    int n = n0 + nBase + in;
    float bias = bz[n] + bpi[n] + bpo[n] + B1v[n];
#pragma unroll
    for (int im = 0; im < 4; ++im) acc[im][in] += bias;
  }
#pragma unroll
  for (int im = 0; im < 4; ++im) {
    int b = bRow + mBase + im;
    float4 v = make_float4(acc[im][0], acc[im][1], acc[im][2], acc[im][3]);
    *(float4*)&L1[(size_t)b * D1_ + n0 + nBase] = v;
  }
}

// ---------------- K3: h1 = tanh([L1|dense] @ W1 + b1) --------------------
__global__ __launch_bounds__(256) void mlp1(
    const float* __restrict__ L1, const float* __restrict__ dense,
    const float* __restrict__ W1, const float* __restrict__ b1,
    float* __restrict__ H1) {
  __shared__ float xs[8][272];
  int b0 = blockIdx.x * 8;
  int t  = threadIdx.x;
#pragma unroll
  for (int r = 0; r < 2; ++r) {
    int idx = r * 1024 + t * 4;
    int bb = idx >> 8, c = idx & 255;
    *(float4*)&xs[bb][c] = *(const float4*)&L1[(size_t)(b0 + bb) * D1_ + c];
  }
  if (t < 128) {
    int bb = t >> 4, j = t & 15;
    xs[bb][256 + j] = dense[(size_t)(b0 + bb) * DD_ + j];
  }
  __syncthreads();
  float acc[8];
#pragma unroll
  for (int bb = 0; bb < 8; ++bb) acc[bb] = b1[t];
  for (int k = 0; k < 272; ++k) {
    float w = W1[(size_t)k * D1_ + t];
#pragma unroll
    for (int bb = 0; bb < 8; ++bb) acc[bb] += xs[bb][k] * w;
  }
#pragma unroll
  for (int bb = 0; bb < 8; ++bb)
    H1[(size_t)(b0 + bb) * D1_ + t] = tanhf(acc[bb]);
}

// ---------------- K4: h2 = tanh(h1@W2+b2); out = h2@W3 + b3 --------------
__global__ __launch_bounds__(128) void mlp2(
    const float* __restrict__ H1, const float* __restrict__ W2,
    const float* __restrict__ b2, const float* __restrict__ W3,
    const float* __restrict__ b3, float* __restrict__ out) {
  __shared__ float hs[16 * 256];
  __shared__ float h2s[16 * 129];
  int b0 = blockIdx.x * 16;
  int t  = threadIdx.x;
#pragma unroll
  for (int r = 0; r < 8; ++r) {
    int idx = r * 512 + t * 4;
    *(float4*)&hs[idx] = *(const float4*)&H1[(size_t)b0 * D1_ + idx];
  }
  __syncthreads();
  float acc[16];
#pragma unroll
  for (int bb = 0; bb < 16; ++bb) acc[bb] = b2[t];
  for (int k = 0; k < 256; ++k) {
    float w = W2[(size_t)k * L2N_ + t];
#pragma unroll
    for (int bb = 0; bb < 16; ++bb) acc[bb] += hs[bb * 256 + k] * w;
  }
#pragma unroll
  for (int bb = 0; bb < 16; ++bb) h2s[bb * 129 + t] = tanhf(acc[bb]);
  __syncthreads();
  int bb = t >> 3, g = t & 7;
  float sum = 0.f;
#pragma unroll
  for (int r = 0; r < 16; ++r) {
    int j = g + 8 * r;
    sum += h2s[bb * 129 + j] * W3[j];
  }
  sum += __shfl_xor(sum, 4, 64);
  sum += __shfl_xor(sum, 2, 64);
  sum += __shfl_xor(sum, 1, 64);
  if (g == 0) out[b0 + bb] = sum + b3[0];
}

extern "C" void kernel_launch(void* const* d_in, const int* in_sizes, int n_in,
                              void* d_out, int out_size, void* d_ws, size_t ws_size,
                              hipStream_t stream) {
  const int*   sparse = (const int*)  d_in[0];
  const float* dense  = (const float*)d_in[1];
  const float* tables = (const float*)d_in[2];
  const float* Wz     = (const float*)d_in[3];
  const float* bz     = (const float*)d_in[4];
  const float* Wpi    = (const float*)d_in[5];
  const float* bpi    = (const float*)d_in[6];
  const float* Wpo    = (const float*)d_in[7];
  const float* bpo    = (const float*)d_in[8];
  const float* B1v    = (const float*)d_in[9];
  const float* W1     = (const float*)d_in[10];
  const float* b1     = (const float*)d_in[11];
  const float* W2     = (const float*)d_in[12];
  const float* b2     = (const float*)d_in[13];
  const float* W3     = (const float*)d_in[14];
  const float* b3     = (const float*)d_in[15];
  float* out = (float*)d_out;

  float* ws = (float*)d_ws;
  float* X  = ws;                 // B*3072
  float* WT = ws + 12582912;      // 7168*256
  float* S  = ws + 14417920;      // B*64
  float* L1 = ws + 14680064;      // B*256
  float* H1 = ws + 15728640;      // B*256

  prep_wt     <<<dim3(K_TOT),          dim3(256), 0, stream>>>(Wz, Wpi, Wpo, WT);
  gather_feats<<<dim3(B_),             dim3(256), 0, stream>>>(sparse, tables, X, S);
  gemm_l1     <<<dim3(B_/BM, D1_/BN),  dim3(256), 0, stream>>>(X, WT, S, bz, bpi, bpo, B1v, L1);
  mlp1        <<<dim3(B_/8),           dim3(256), 0, stream>>>(L1, dense, W1, b1, H1);
  mlp2        <<<dim3(B_/16),          dim3(128), 0, stream>>>(H1, W2, b2, W3, b3, out);
}

// Round 2
// 156.653 us; speedup vs baseline: 3.4224x; 3.4224x over previous
//
#include <hip/hip_runtime.h>
#include <hip/hip_bf16.h>

#define B_    4096
#define F_    32
#define V_    50000
#define E_    64
#define D1_   256
#define DD_   16
#define L2N_  128
#define KX    3072      // stored X width (emb 2048 | inner 1024)
#define KTOT  7168
#define NKT   112       // KTOT/64
#define NKX   48        // KX/64

typedef __bf16 bf16x8 __attribute__((ext_vector_type(8)));
typedef float  f32x4  __attribute__((ext_vector_type(4)));

typedef __attribute__((address_space(1))) const void gvoid;
typedef __attribute__((address_space(3))) void svoid;

__device__ __forceinline__ ushort f2b(float f){
  __bf16 h = (__bf16)f; return __builtin_bit_cast(ushort, h);
}
__device__ __forceinline__ uint packbf(float a, float b){
  union { uint u; __bf16 h[2]; } p; p.h[0] = (__bf16)a; p.h[1] = (__bf16)b; return p.u;
}
__device__ __forceinline__ void gload16(const void* g, void* l){
  __builtin_amdgcn_global_load_lds((gvoid*)g, (svoid*)l, 16, 0, 0);
}

// ---------------- K0: WB[n][k] bf16 = concat(Wz[n,:], Wpi[n,:], Wpo[n,:]) ---
__global__ __launch_bounds__(256) void prep_wt(
    const float* __restrict__ Wz, const float* __restrict__ Wpi,
    const float* __restrict__ Wpo, ushort* __restrict__ WBb) {
  int n = blockIdx.x, t = threadIdx.x;
#pragma unroll
  for (int j = 0; j < 7; ++j) {
    int k4 = (j * 256 + t) * 4;
    float4 v;
    if (k4 < 2048)      v = *(const float4*)&Wz [(size_t)n * 2048 + k4];
    else if (k4 < 3072) v = *(const float4*)&Wpi[(size_t)n * 1024 + (k4 - 2048)];
    else                v = *(const float4*)&Wpo[(size_t)n * 4096 + (k4 - 3072)];
    ushort4 o = make_ushort4(f2b(v.x), f2b(v.y), f2b(v.z), f2b(v.w));
    *(ushort4*)&WBb[(size_t)n * KTOT + k4] = o;
  }
}

// ---------------- K1: gather emb (bf16 X), s (fp32), gram inner (bf16 X) ----
__global__ __launch_bounds__(256) void gather_feats(
    const int* __restrict__ sparse, const float* __restrict__ tables,
    ushort* __restrict__ Xb, float* __restrict__ S) {
  int b = blockIdx.x, t = threadIdx.x;
  __shared__ float emb[F_ * 65];
  const int* sp = sparse + b * F_;
  int e = t & 63, f0 = t >> 6;
#pragma unroll
  for (int r = 0; r < 8; ++r) {
    int f = f0 + r * 4;
    int idx = sp[f];
    float v = tables[((size_t)f * V_ + idx) * E_ + e];
    emb[f * 65 + e] = v;
    Xb[(size_t)b * KX + f * 64 + e] = f2b(v);
  }
  __syncthreads();
  if (t < 64) {
    float a = 0.f;
#pragma unroll
    for (int f = 0; f < F_; ++f) a += emb[f * 65 + t];
    S[(size_t)b * 64 + t] = a;
  }
#pragma unroll
  for (int r = 0; r < 4; ++r) {
    int p = t + 256 * r;
    int i = p >> 5, j = p & 31;
    const float* ei = emb + i * 65;
    const float* ej = emb + j * 65;
    float a = 0.f;
#pragma unroll
    for (int q = 0; q < E_; ++q) a += ei[q] * ej[q];
    Xb[(size_t)b * KX + 2048 + p] = f2b(a);
  }
}

// ---------------- K2: L1 = [X | outer(s)] @ WB^T + bias, bf16 MFMA ---------
__global__ __launch_bounds__(256, 1) void gemm_l1(
    const ushort* __restrict__ Xb, const ushort* __restrict__ WBb,
    const float* __restrict__ S,
    const float* __restrict__ bz, const float* __restrict__ bpi,
    const float* __restrict__ bpo, const float* __restrict__ B1v,
    float* __restrict__ L1) {
  __shared__ __align__(16) ushort As[2][64 * 64];
  __shared__ __align__(16) ushort Bs[2][64 * 64];
  __shared__ float Ss[64 * 65];          // s rows fp32, stride 65 (conflict-free)

  int bid = blockIdx.x;
  int lg  = (bid & 7) * 32 + (bid >> 3); // XCD-chunked: XCD x owns 32 logical tiles
  int mT  = lg >> 2, nT = lg & 3;        // N-fastest: 4 N-tiles of an M-tile share L2
  int bRow = mT * 64, n0 = nT * 64;

  int tid = threadIdx.x;
  int w = tid >> 6, l = tid & 63;
  int wm = (w >> 1) * 32, wn = (w & 1) * 32;

  // ---- stage Ss: 64 s-rows fp32
#pragma unroll
  for (int p = 0; p < 4; ++p) {
    int idx = p * 1024 + tid * 4;
    float4 v = *(const float4*)&S[(size_t)bRow * 64 + idx];
    int m = idx >> 6, c = idx & 63;
    float* dst = &Ss[m * 65 + c];
    dst[0] = v.x; dst[1] = v.y; dst[2] = v.z; dst[3] = v.w;
  }

  // ---- per-lane packed-bf16 s values for outer-region fragment synthesis.
  // Lane only ever supplies k = ks*32 + (l>>4)*8 + j  ->  8 uints per row, static idx.
  uint sreg[2][8];
#pragma unroll
  for (int mi = 0; mi < 2; ++mi) {
    int grow = bRow + wm + mi * 16 + (l & 15);
    const float* base = S + (size_t)grow * 64 + (l >> 4) * 8;
#pragma unroll
    for (int ks = 0; ks < 2; ++ks) {
      float4 v0 = *(const float4*)(base + ks * 32);
      float4 v1 = *(const float4*)(base + ks * 32 + 4);
      sreg[mi][ks * 4 + 0] = packbf(v0.x, v0.y);
      sreg[mi][ks * 4 + 1] = packbf(v0.z, v0.w);
      sreg[mi][ks * 4 + 2] = packbf(v1.x, v1.y);
      sreg[mi][ks * 4 + 3] = packbf(v1.z, v1.w);
    }
  }

  // staging: chunk = 8 rows x 128B; dest slot sd=l&7, row lr=l>>3;
  // source slot = sd ^ lr  (inverse swizzle on global side, LDS stays linear)
  int lr = l >> 3;
  int lsg = (l & 7) ^ lr;

  auto stageA = [&](int bufI, int kt) {
    const ushort* s0 = Xb + (size_t)(bRow + w * 16 + lr) * KX + (size_t)kt * 64 + lsg * 8;
    gload16(s0, &As[bufI][(w * 2 + 0) * 512]);
    gload16(s0 + (size_t)8 * KX, &As[bufI][(w * 2 + 1) * 512]);
  };
  auto stageB = [&](int bufI, int kt) {
    const ushort* s0 = WBb + (size_t)(n0 + w * 16 + lr) * KTOT + (size_t)kt * 64 + lsg * 8;
    gload16(s0, &Bs[bufI][(w * 2 + 0) * 512]);
    gload16(s0 + (size_t)8 * KTOT, &Bs[bufI][(w * 2 + 1) * 512]);
  };

  f32x4 acc[2][2] = {};
  int buf = 0;
  stageA(0, 0);
  stageB(0, 0);
  __syncthreads();

  for (int kt = 0; kt < NKT; ++kt) {
    int nxt = kt + 1;
    if (nxt < NKT) {
      if (nxt < NKX) stageA(buf ^ 1, nxt);
      stageB(buf ^ 1, nxt);
    }

    bf16x8 af[2][2], bf[2][2];
#pragma unroll
    for (int ni = 0; ni < 2; ++ni) {
      int row = wn + ni * 16 + (l & 15);
#pragma unroll
      for (int ks = 0; ks < 2; ++ks) {
        int slot = (ks * 4 + (l >> 4)) ^ (row & 7);
        bf[ni][ks] = *(const bf16x8*)&Bs[buf][row * 64 + slot * 8];
      }
    }
    if (kt < NKX) {
#pragma unroll
      for (int mi = 0; mi < 2; ++mi) {
        int row = wm + mi * 16 + (l & 15);
#pragma unroll
        for (int ks = 0; ks < 2; ++ks) {
          int slot = (ks * 4 + (l >> 4)) ^ (row & 7);
          af[mi][ks] = *(const bf16x8*)&As[buf][row * 64 + slot * 8];
        }
      }
    } else {
      int i = kt - NKX;  // uniform outer index: A[m][jj] = s[m][i]*s[m][jj]
#pragma unroll
      for (int mi = 0; mi < 2; ++mi) {
        float si = Ss[(wm + mi * 16 + (l & 15)) * 65 + i];
#pragma unroll
        for (int ks = 0; ks < 2; ++ks) {
          bf16x8 a;
#pragma unroll
          for (int j2 = 0; j2 < 4; ++j2) {
            uint u = sreg[mi][ks * 4 + j2];
            float g0 = __uint_as_float(u << 16);
            float g1 = __uint_as_float(u & 0xffff0000u);
            a[2 * j2]     = (__bf16)(si * g0);
            a[2 * j2 + 1] = (__bf16)(si * g1);
          }
          af[mi][ks] = a;
        }
      }
    }
#pragma unroll
    for (int ks = 0; ks < 2; ++ks)
#pragma unroll
      for (int mi = 0; mi < 2; ++mi)
#pragma unroll
        for (int ni = 0; ni < 2; ++ni)
          acc[mi][ni] = __builtin_amdgcn_mfma_f32_16x16x32_bf16(
              af[mi][ks], bf[ni][ks], acc[mi][ni], 0, 0, 0);
    __syncthreads();
    buf ^= 1;
  }

  // epilogue: C/D map col=l&15, row=(l>>4)*4+r  (m89-verified)
#pragma unroll
  for (int ni = 0; ni < 2; ++ni) {
    int col = n0 + wn + ni * 16 + (l & 15);
    float bias = bz[col] + bpi[col] + bpo[col] + B1v[col];
#pragma unroll
    for (int mi = 0; mi < 2; ++mi) {
      int row0 = bRow + wm + mi * 16 + (l >> 4) * 4;
#pragma unroll
      for (int r = 0; r < 4; ++r)
        L1[(size_t)(row0 + r) * D1_ + col] = acc[mi][ni][r] + bias;
    }
  }
}

// ---------------- K3: h1 = tanh([L1|dense] @ W1 + b1) ----------------------
__global__ __launch_bounds__(256) void mlp1(
    const float* __restrict__ L1, const float* __restrict__ dense,
    const float* __restrict__ W1, const float* __restrict__ b1,
    float* __restrict__ H1) {
  __shared__ float xs[8][272];
  int b0 = blockIdx.x * 8;
  int t  = threadIdx.x;
#pragma unroll
  for (int r = 0; r < 2; ++r) {
    int idx = r * 1024 + t * 4;
    int bb = idx >> 8, c = idx & 255;
    *(float4*)&xs[bb][c] = *(const float4*)&L1[(size_t)(b0 + bb) * D1_ + c];
  }
  if (t < 128) {
    int bb = t >> 4, j = t & 15;
    xs[bb][256 + j] = dense[(size_t)(b0 + bb) * DD_ + j];
  }
  __syncthreads();
  float acc[8];
#pragma unroll
  for (int bb = 0; bb < 8; ++bb) acc[bb] = b1[t];
  for (int k = 0; k < 272; ++k) {
    float w = W1[(size_t)k * D1_ + t];
#pragma unroll
    for (int bb = 0; bb < 8; ++bb) acc[bb] += xs[bb][k] * w;
  }
#pragma unroll
  for (int bb = 0; bb < 8; ++bb)
    H1[(size_t)(b0 + bb) * D1_ + t] = tanhf(acc[bb]);
}

// ---------------- K4: h2 = tanh(h1@W2+b2); out = h2@W3 + b3 ----------------
__global__ __launch_bounds__(128) void mlp2(
    const float* __restrict__ H1, const float* __restrict__ W2,
    const float* __restrict__ b2, const float* __restrict__ W3,
    const float* __restrict__ b3, float* __restrict__ out) {
  __shared__ float hs[16 * 256];
  __shared__ float h2s[16 * 129];
  int b0 = blockIdx.x * 16;
  int t  = threadIdx.x;
#pragma unroll
  for (int r = 0; r < 8; ++r) {
    int idx = r * 512 + t * 4;
    *(float4*)&hs[idx] = *(const float4*)&H1[(size_t)b0 * D1_ + idx];
  }
  __syncthreads();
  float acc[16];
#pragma unroll
  for (int bb = 0; bb < 16; ++bb) acc[bb] = b2[t];
  for (int k = 0; k < 256; ++k) {
    float w = W2[(size_t)k * L2N_ + t];
#pragma unroll
    for (int bb = 0; bb < 16; ++bb) acc[bb] += hs[bb * 256 + k] * w;
  }
#pragma unroll
  for (int bb = 0; bb < 16; ++bb) h2s[bb * 129 + t] = tanhf(acc[bb]);
  __syncthreads();
  int bb = t >> 3, g = t & 7;
  float sum = 0.f;
#pragma unroll
  for (int r = 0; r < 16; ++r) {
    int j = g + 8 * r;
    sum += h2s[bb * 129 + j] * W3[j];
  }
  sum += __shfl_xor(sum, 4, 64);
  sum += __shfl_xor(sum, 2, 64);
  sum += __shfl_xor(sum, 1, 64);
  if (g == 0) out[b0 + bb] = sum + b3[0];
}

extern "C" void kernel_launch(void* const* d_in, const int* in_sizes, int n_in,
                              void* d_out, int out_size, void* d_ws, size_t ws_size,
                              hipStream_t stream) {
  const int*   sparse = (const int*)  d_in[0];
  const float* dense  = (const float*)d_in[1];
  const float* tables = (const float*)d_in[2];
  const float* Wz     = (const float*)d_in[3];
  const float* bz     = (const float*)d_in[4];
  const float* Wpi    = (const float*)d_in[5];
  const float* bpi    = (const float*)d_in[6];
  const float* Wpo    = (const float*)d_in[7];
  const float* bpo    = (const float*)d_in[8];
  const float* B1v    = (const float*)d_in[9];
  const float* W1     = (const float*)d_in[10];
  const float* b1     = (const float*)d_in[11];
  const float* W2     = (const float*)d_in[12];
  const float* b2     = (const float*)d_in[13];
  const float* W3     = (const float*)d_in[14];
  const float* b3     = (const float*)d_in[15];
  float* out = (float*)d_out;

  // ws layout (bytes), total 38.3 MB
  char* ws = (char*)d_ws;
  ushort* Xb  = (ushort*)(ws);               // 4096*3072*2 = 25,165,824
  ushort* WBb = (ushort*)(ws + 25165824);    // 256*7168*2  =  3,670,016
  float*  S   = (float*) (ws + 28835840);    // 4096*64*4   =  1,048,576
  float*  L1  = (float*) (ws + 29884416);    // 4096*256*4  =  4,194,304
  float*  H1  = (float*) (ws + 34078720);    // 4096*256*4  =  4,194,304

  prep_wt     <<<dim3(256),  dim3(256), 0, stream>>>(Wz, Wpi, Wpo, WBb);
  gather_feats<<<dim3(4096), dim3(256), 0, stream>>>(sparse, tables, Xb, S);
  gemm_l1     <<<dim3(256),  dim3(256), 0, stream>>>(Xb, WBb, S, bz, bpi, bpo, B1v, L1);
  mlp1        <<<dim3(512),  dim3(256), 0, stream>>>(L1, dense, W1, b1, H1);
  mlp2        <<<dim3(256),  dim3(128), 0, stream>>>(H1, W2, b2, W3, b3, out);
}

// Round 3
// 93.640 us; speedup vs baseline: 5.7255x; 1.6729x over previous
//
#include <hip/hip_runtime.h>
#include <hip/hip_bf16.h>

#define B_    4096
#define F_    32
#define V_    50000
#define E_    64
#define D1_   256
#define DD_   16
#define L2N_  128
#define KX    3072      // stored X width (emb 2048 | inner 1024)
#define KTOT  7168

typedef __bf16 bf16x8 __attribute__((ext_vector_type(8)));
typedef float  f32x4  __attribute__((ext_vector_type(4)));

typedef __attribute__((address_space(1))) const void gvoid;
typedef __attribute__((address_space(3))) void svoid;

__device__ __forceinline__ ushort f2b(float f){
  __bf16 h = (__bf16)f; return __builtin_bit_cast(ushort, h);
}
__device__ __forceinline__ float b2f(ushort u){
  return __uint_as_float(((uint)u) << 16);
}
__device__ __forceinline__ void gload16(const void* g, void* l){
  __builtin_amdgcn_global_load_lds((gvoid*)g, (svoid*)l, 16, 0, 0);
}

// ============ K0: weight prep ============
// blocks 0..255   : WBb[n][0:7168] = bf16 concat(Wz[n], Wpi[n], Wpo[n])
// blocks 256..511 : W1b[n][0:288]  = bf16 W1[k][n], zero-pad k>=272
// blocks 512..639 : W2b[n][0:256]  = bf16 W2[k][n]
__global__ __launch_bounds__(256) void prep_w(
    const float* __restrict__ Wz, const float* __restrict__ Wpi,
    const float* __restrict__ Wpo, const float* __restrict__ W1,
    const float* __restrict__ W2,
    ushort* __restrict__ WBb, ushort* __restrict__ W1b, ushort* __restrict__ W2b) {
  int bid = blockIdx.x, t = threadIdx.x;
  if (bid < 256) {
    int n = bid;
#pragma unroll
    for (int j = 0; j < 7; ++j) {
      int k4 = (j * 256 + t) * 4;
      float4 v;
      if (k4 < 2048)      v = *(const float4*)&Wz [(size_t)n * 2048 + k4];
      else if (k4 < 3072) v = *(const float4*)&Wpi[(size_t)n * 1024 + (k4 - 2048)];
      else                v = *(const float4*)&Wpo[(size_t)n * 4096 + (k4 - 3072)];
      ushort4 o = make_ushort4(f2b(v.x), f2b(v.y), f2b(v.z), f2b(v.w));
      *(ushort4*)&WBb[(size_t)n * KTOT + k4] = o;
    }
  } else if (bid < 512) {
    int n = bid - 256;
    float v0 = (t < 272) ? W1[(size_t)t * 256 + n] : 0.f;
    W1b[(size_t)n * 288 + t] = f2b(v0);
    if (t < 32) {
      int k2 = 256 + t;
      float v1 = (k2 < 272) ? W1[(size_t)k2 * 256 + n] : 0.f;
      W1b[(size_t)n * 288 + k2] = f2b(v1);
    }
  } else {
    int n = bid - 512;
    W2b[(size_t)n * 256 + t] = f2b(W2[(size_t)t * 128 + n]);
  }
}

// ============ K1: L1 := bias (bz+bpi+bpo+B1), per row ============
__global__ __launch_bounds__(256) void init_l1(
    const float* __restrict__ bz, const float* __restrict__ bpi,
    const float* __restrict__ bpo, const float* __restrict__ B1v,
    float* __restrict__ L1) {
  int c = threadIdx.x;
  float v = bz[c] + bpi[c] + bpo[c] + B1v[c];
  int r0 = blockIdx.x * 16;
#pragma unroll
  for (int r = 0; r < 16; ++r)
    L1[(size_t)(r0 + r) * D1_ + c] = v;
}

// ============ K2: gather emb -> Xb(bf16), s -> S(fp32), gram via MFMA ======
// 1 wave = 1 sample. Fragments straight from global; B-frag == A-frag for gram.
__global__ __launch_bounds__(256) void gather_feats(
    const int* __restrict__ sparse, const float* __restrict__ tables,
    ushort* __restrict__ Xb, float* __restrict__ S) {
  int w = threadIdx.x >> 6, l = threadIdx.x & 63;
  int b = blockIdx.x * 4 + w;
  int fr = l & 15, q = l >> 4;

  int i0 = sparse[b * F_ + fr];
  int i1 = sparse[b * F_ + 16 + fr];
  const float* r0 = tables + ((size_t)fr * V_ + i0) * 64;
  const float* r1 = tables + ((size_t)(16 + fr) * V_ + i1) * 64;

  // v[rh][ks][half]: 8 fp32 of emb[rh*16+fr][ks*32 + q*8 .. +8]
  float4 v[2][2][2];
#pragma unroll
  for (int ks = 0; ks < 2; ++ks) {
    v[0][ks][0] = *(const float4*)(r0 + ks * 32 + q * 8);
    v[0][ks][1] = *(const float4*)(r0 + ks * 32 + q * 8 + 4);
    v[1][ks][0] = *(const float4*)(r1 + ks * 32 + q * 8);
    v[1][ks][1] = *(const float4*)(r1 + ks * 32 + q * 8 + 4);
  }

  // pack bf16 fragments + store emb region of Xb
  bf16x8 fg[2][2];
#pragma unroll
  for (int rh = 0; rh < 2; ++rh)
#pragma unroll
    for (int ks = 0; ks < 2; ++ks) {
      bf16x8 a;
      a[0] = (__bf16)v[rh][ks][0].x; a[1] = (__bf16)v[rh][ks][0].y;
      a[2] = (__bf16)v[rh][ks][0].z; a[3] = (__bf16)v[rh][ks][0].w;
      a[4] = (__bf16)v[rh][ks][1].x; a[5] = (__bf16)v[rh][ks][1].y;
      a[6] = (__bf16)v[rh][ks][1].z; a[7] = (__bf16)v[rh][ks][1].w;
      fg[rh][ks] = a;
      *(bf16x8*)&Xb[(size_t)b * KX + (rh * 16 + fr) * 64 + ks * 32 + q * 8] = a;
    }

  // s = column sums: reduce over 32 rows = (rh pair) + shfl over l&15
  float sv[2][8];
#pragma unroll
  for (int ks = 0; ks < 2; ++ks) {
    sv[ks][0] = v[0][ks][0].x + v[1][ks][0].x; sv[ks][1] = v[0][ks][0].y + v[1][ks][0].y;
    sv[ks][2] = v[0][ks][0].z + v[1][ks][0].z; sv[ks][3] = v[0][ks][0].w + v[1][ks][0].w;
    sv[ks][4] = v[0][ks][1].x + v[1][ks][1].x; sv[ks][5] = v[0][ks][1].y + v[1][ks][1].y;
    sv[ks][6] = v[0][ks][1].z + v[1][ks][1].z; sv[ks][7] = v[0][ks][1].w + v[1][ks][1].w;
  }
#pragma unroll
  for (int m = 1; m < 16; m <<= 1)
#pragma unroll
    for (int ks = 0; ks < 2; ++ks)
#pragma unroll
      for (int j = 0; j < 8; ++j)
        sv[ks][j] += __shfl_xor(sv[ks][j], m, 64);
  if (fr == 0) {
#pragma unroll
    for (int ks = 0; ks < 2; ++ks) {
      float4 o0 = make_float4(sv[ks][0], sv[ks][1], sv[ks][2], sv[ks][3]);
      float4 o1 = make_float4(sv[ks][4], sv[ks][5], sv[ks][6], sv[ks][7]);
      *(float4*)&S[(size_t)b * 64 + ks * 32 + q * 8]     = o0;
      *(float4*)&S[(size_t)b * 64 + ks * 32 + q * 8 + 4] = o1;
    }
  }

  // gram: inner = emb @ emb^T via 8 MFMA (B-frag == A-frag)
  f32x4 t[2][2] = {};
#pragma unroll
  for (int ks = 0; ks < 2; ++ks)
#pragma unroll
    for (int ri = 0; ri < 2; ++ri)
#pragma unroll
      for (int rj = 0; rj < 2; ++rj)
        t[ri][rj] = __builtin_amdgcn_mfma_f32_16x16x32_bf16(
            fg[ri][ks], fg[rj][ks], t[ri][rj], 0, 0, 0);

#pragma unroll
  for (int ri = 0; ri < 2; ++ri)
#pragma unroll
    for (int rj = 0; rj < 2; ++rj)
#pragma unroll
      for (int r = 0; r < 4; ++r) {
        int rowi = ri * 16 + q * 4 + r;
        int colj = rj * 16 + fr;
        Xb[(size_t)b * KX + 2048 + rowi * 32 + colj] = f2b(t[ri][rj][r]);
      }
}

// ============ K3: split-K MFMA GEMM, atomicAdd into L1 ============
// grid 256 = 32 mT x 4 nT x 2 kc. Each block: 24 X-kts + 32 outer-kts.
#define BM 128
#define BN 64
__global__ __launch_bounds__(256, 2) void gemm_l1(
    const ushort* __restrict__ Xb, const ushort* __restrict__ WBb,
    const float* __restrict__ S, float* __restrict__ L1) {
  __shared__ __align__(16) ushort As[2][BM * 64];   // 32 KB
  __shared__ __align__(16) ushort Bs[2][BN * 64];   // 16 KB
  __shared__ ushort Ssb[BM * 68];                   // 17.4 KB (bf16 s rows)

  int bid = blockIdx.x;
  int lg  = (bid & 7) * 32 + (bid >> 3);   // XCD-chunked
  int kc  = lg >> 7;                       // 0..1
  int nT  = (lg >> 5) & 3;                 // 0..3  (fixed per XCD -> B L2-hot)
  int mT  = lg & 31;                       // 0..31
  int bRow = mT * BM, n0 = nT * BN;

  int tid = threadIdx.x, w = tid >> 6, l = tid & 63;
  int wm = (w >> 1) * 64, wn = (w & 1) * 32;

  // ---- stage Ssb (bf16 s rows, pad 68)
#pragma unroll
  for (int p = 0; p < 8; ++p) {
    int idx = p * 1024 + tid * 4;
    int row = idx >> 6, c = idx & 63;
    float4 v = *(const float4*)&S[(size_t)bRow * 64 + idx];
    uint u0 = ((uint)f2b(v.x)) | (((uint)f2b(v.y)) << 16);
    uint u1 = ((uint)f2b(v.z)) | (((uint)f2b(v.w)) << 16);
    *(uint*)&Ssb[row * 68 + c]     = u0;
    *(uint*)&Ssb[row * 68 + c + 2] = u1;
  }

  // ---- per-lane fp32 s fragment values for outer synthesis (all static idx)
  float sregf[4][16];
#pragma unroll
  for (int mi = 0; mi < 4; ++mi) {
    const float* base = S + (size_t)(bRow + wm + mi * 16 + (l & 15)) * 64 + (l >> 4) * 8;
#pragma unroll
    for (int ks = 0; ks < 2; ++ks) {
      float4 a0 = *(const float4*)(base + ks * 32);
      float4 a1 = *(const float4*)(base + ks * 32 + 4);
      sregf[mi][ks * 8 + 0] = a0.x; sregf[mi][ks * 8 + 1] = a0.y;
      sregf[mi][ks * 8 + 2] = a0.z; sregf[mi][ks * 8 + 3] = a0.w;
      sregf[mi][ks * 8 + 4] = a1.x; sregf[mi][ks * 8 + 5] = a1.y;
      sregf[mi][ks * 8 + 6] = a1.z; sregf[mi][ks * 8 + 7] = a1.w;
    }
  }

  int r8 = l >> 3;
  int sg = ((l & 7) ^ r8) * 8;   // inverse-swizzled source slot

  auto stageA = [&](int bI, int kt) {   // 128x64 tile: wave w rows w*32+c*8+r8
    const ushort* src = Xb + (size_t)(bRow + w * 32 + r8) * KX + kt * 64 + sg;
#pragma unroll
    for (int c = 0; c < 4; ++c)
      gload16(src + (size_t)(c * 8) * KX, &As[bI][(w * 32 + c * 8) * 64]);
  };
  auto stageB = [&](int bI, int kt) {   // 64x64 tile: wave w rows w*16+c*8+r8
    const ushort* src = WBb + (size_t)(n0 + w * 16 + r8) * KTOT + kt * 64 + sg;
#pragma unroll
    for (int c = 0; c < 2; ++c)
      gload16(src + (size_t)(c * 8) * KTOT, &Bs[bI][(w * 16 + c * 8) * 64]);
  };

  f32x4 acc[4][2] = {};
  bf16x8 af[4][2], bfr[2][2];
  int buf = 0;

  // ================= X phase: kts [kc*24, kc*24+24) =================
  int kt0 = kc * 24;
  stageA(0, kt0); stageB(0, kt0);
  __syncthreads();
  for (int t = 0; t < 24; ++t) {
    if (t + 1 < 24) { stageA(buf ^ 1, kt0 + t + 1); stageB(buf ^ 1, kt0 + t + 1); }
#pragma unroll
    for (int mi = 0; mi < 4; ++mi) {
      int row = wm + mi * 16 + (l & 15);
#pragma unroll
      for (int ks = 0; ks < 2; ++ks) {
        int slot = (ks * 4 + (l >> 4)) ^ (row & 7);
        af[mi][ks] = *(const bf16x8*)&As[buf][row * 64 + slot * 8];
      }
    }
#pragma unroll
    for (int ni = 0; ni < 2; ++ni) {
      int col = wn + ni * 16 + (l & 15);
#pragma unroll
      for (int ks = 0; ks < 2; ++ks) {
        int slot = (ks * 4 + (l >> 4)) ^ (col & 7);
        bfr[ni][ks] = *(const bf16x8*)&Bs[buf][col * 64 + slot * 8];
      }
    }
#pragma unroll
    for (int ks = 0; ks < 2; ++ks)
#pragma unroll
      for (int mi = 0; mi < 4; ++mi)
#pragma unroll
        for (int ni = 0; ni < 2; ++ni)
          acc[mi][ni] = __builtin_amdgcn_mfma_f32_16x16x32_bf16(
              af[mi][ks], bfr[ni][ks], acc[mi][ni], 0, 0, 0);
    __syncthreads();
    buf ^= 1;
  }

  // ================= outer phase: i in [kc*32, kc*32+32) =============
  int i0 = kc * 32;
  stageB(buf, 48 + i0);
  __syncthreads();
  for (int t = 0; t < 32; ++t) {
    if (t + 1 < 32) stageB(buf ^ 1, 48 + i0 + t + 1);
    int i = i0 + t;
#pragma unroll
    for (int mi = 0; mi < 4; ++mi) {
      int row = wm + mi * 16 + (l & 15);
      float si = b2f(Ssb[row * 68 + i]);
#pragma unroll
      for (int ks = 0; ks < 2; ++ks) {
        bf16x8 a;
#pragma unroll
        for (int j = 0; j < 8; ++j)
          a[j] = (__bf16)(si * sregf[mi][ks * 8 + j]);
        af[mi][ks] = a;
      }
    }
#pragma unroll
    for (int ni = 0; ni < 2; ++ni) {
      int col = wn + ni * 16 + (l & 15);
#pragma unroll
      for (int ks = 0; ks < 2; ++ks) {
        int slot = (ks * 4 + (l >> 4)) ^ (col & 7);
        bfr[ni][ks] = *(const bf16x8*)&Bs[buf][col * 64 + slot * 8];
      }
    }
#pragma unroll
    for (int ks = 0; ks < 2; ++ks)
#pragma unroll
      for (int mi = 0; mi < 4; ++mi)
#pragma unroll
        for (int ni = 0; ni < 2; ++ni)
          acc[mi][ni] = __builtin_amdgcn_mfma_f32_16x16x32_bf16(
              af[mi][ks], bfr[ni][ks], acc[mi][ni], 0, 0, 0);
    __syncthreads();
    buf ^= 1;
  }

  // ---- epilogue: atomic accumulate partial tile
#pragma unroll
  for (int mi = 0; mi < 4; ++mi) {
    int row0 = bRow + wm + mi * 16 + (l >> 4) * 4;
#pragma unroll
    for (int ni = 0; ni < 2; ++ni) {
      int col = n0 + wn + ni * 16 + (l & 15);
#pragma unroll
      for (int r = 0; r < 4; ++r)
        atomicAdd(&L1[(size_t)(row0 + r) * D1_ + col], acc[mi][ni][r]);
    }
  }
}

// ============ K4: fused MLP (layer1+layer2+head), MFMA ============
__global__ __launch_bounds__(256) void mlp_fused(
    const float* __restrict__ L1, const float* __restrict__ dense,
    const ushort* __restrict__ W1b, const ushort* __restrict__ W2b,
    const float* __restrict__ b1, const float* __restrict__ b2,
    const float* __restrict__ W3, const float* __restrict__ b3,
    float* __restrict__ out) {
  __shared__ ushort hs[16 * 264];
  __shared__ ushort h2s[16 * 136];
  int b0 = blockIdx.x * 16;
  int tid = threadIdx.x, w = tid >> 6, l = tid & 63;
  int row = l & 15, q = l >> 4;
  int wn = w * 64;

  // ---- layer 1: [L1|dense|0pad] (K=288) @ W1b^T -> 256 cols
  f32x4 acc1[4] = {};
  for (int kt = 0; kt < 9; ++kt) {
    int k0 = kt * 32 + q * 8;
    bf16x8 afr;
    if (kt < 8) {
      float4 u0 = *(const float4*)&L1[(size_t)(b0 + row) * D1_ + k0];
      float4 u1 = *(const float4*)&L1[(size_t)(b0 + row) * D1_ + k0 + 4];
      afr[0] = (__bf16)u0.x; afr[1] = (__bf16)u0.y; afr[2] = (__bf16)u0.z; afr[3] = (__bf16)u0.w;
      afr[4] = (__bf16)u1.x; afr[5] = (__bf16)u1.y; afr[6] = (__bf16)u1.z; afr[7] = (__bf16)u1.w;
    } else if (q < 2) {
      float4 u0 = *(const float4*)&dense[(size_t)(b0 + row) * DD_ + q * 8];
      float4 u1 = *(const float4*)&dense[(size_t)(b0 + row) * DD_ + q * 8 + 4];
      afr[0] = (__bf16)u0.x; afr[1] = (__bf16)u0.y; afr[2] = (__bf16)u0.z; afr[3] = (__bf16)u0.w;
      afr[4] = (__bf16)u1.x; afr[5] = (__bf16)u1.y; afr[6] = (__bf16)u1.z; afr[7] = (__bf16)u1.w;
    } else {
      afr = (bf16x8)(__bf16)0.f;
    }
#pragma unroll
    for (int ni = 0; ni < 4; ++ni) {
      bf16x8 bfr = *(const bf16x8*)&W1b[(size_t)(wn + ni * 16 + row) * 288 + k0];
      acc1[ni] = __builtin_amdgcn_mfma_f32_16x16x32_bf16(afr, bfr, acc1[ni], 0, 0, 0);
    }
  }
#pragma unroll
  for (int ni = 0; ni < 4; ++ni) {
    int col = wn + ni * 16 + row;
    float bias = b1[col];
#pragma unroll
    for (int r = 0; r < 4; ++r)
      hs[(q * 4 + r) * 264 + col] = f2b(tanhf(acc1[ni][r] + bias));
  }
  __syncthreads();

  // ---- layer 2: h (K=256) @ W2b^T -> 128 cols
  int wn2 = w * 32;
  f32x4 acc2[2] = {};
  for (int kt = 0; kt < 8; ++kt) {
    int k0 = kt * 32 + q * 8;
    bf16x8 afr = *(const bf16x8*)&hs[row * 264 + k0];
#pragma unroll
    for (int ni = 0; ni < 2; ++ni) {
      bf16x8 bfr = *(const bf16x8*)&W2b[(size_t)(wn2 + ni * 16 + row) * 256 + k0];
      acc2[ni] = __builtin_amdgcn_mfma_f32_16x16x32_bf16(afr, bfr, acc2[ni], 0, 0, 0);
    }
  }
#pragma unroll
  for (int ni = 0; ni < 2; ++ni) {
    int col = wn2 + ni * 16 + row;
    float bias = b2[col];
#pragma unroll
    for (int r = 0; r < 4; ++r)
      h2s[(q * 4 + r) * 136 + col] = f2b(tanhf(acc2[ni][r] + bias));
  }
  __syncthreads();

  // ---- head: out = h2 @ W3 + b3 (wave 0)
  if (w == 0) {
    int rr = l >> 2, g = l & 3;
    float sum = 0.f;
#pragma unroll
    for (int jj = 0; jj < 32; ++jj) {
      int j = g * 32 + jj;
      sum += b2f(h2s[rr * 136 + j]) * W3[j];
    }
    sum += __shfl_xor(sum, 1, 64);
    sum += __shfl_xor(sum, 2, 64);
    if (g == 0) out[b0 + rr] = sum + b3[0];
  }
}

extern "C" void kernel_launch(void* const* d_in, const int* in_sizes, int n_in,
                              void* d_out, int out_size, void* d_ws, size_t ws_size,
                              hipStream_t stream) {
  const int*   sparse = (const int*)  d_in[0];
  const float* dense  = (const float*)d_in[1];
  const float* tables = (const float*)d_in[2];
  const float* Wz     = (const float*)d_in[3];
  const float* bz     = (const float*)d_in[4];
  const float* Wpi    = (const float*)d_in[5];
  const float* bpi    = (const float*)d_in[6];
  const float* Wpo    = (const float*)d_in[7];
  const float* bpo    = (const float*)d_in[8];
  const float* B1v    = (const float*)d_in[9];
  const float* W1     = (const float*)d_in[10];
  const float* b1     = (const float*)d_in[11];
  const float* W2     = (const float*)d_in[12];
  const float* b2     = (const float*)d_in[13];
  const float* W3     = (const float*)d_in[14];
  const float* b3     = (const float*)d_in[15];
  float* out = (float*)d_out;

  // ws layout (bytes), total ~34.3 MB
  char* ws = (char*)d_ws;
  ushort* Xb  = (ushort*)(ws);               // 4096*3072*2 = 25,165,824
  ushort* WBb = (ushort*)(ws + 25165824);    // 256*7168*2  =  3,670,016
  ushort* W1b = (ushort*)(ws + 28835840);    // 256*288*2   =    147,456
  ushort* W2b = (ushort*)(ws + 28983296);    // 128*256*2   =     65,536
  float*  S   = (float*) (ws + 29048832);    // 4096*64*4   =  1,048,576
  float*  L1  = (float*) (ws + 30097408);    // 4096*256*4  =  4,194,304

  prep_w      <<<dim3(640),  dim3(256), 0, stream>>>(Wz, Wpi, Wpo, W1, W2, WBb, W1b, W2b);
  init_l1     <<<dim3(256),  dim3(256), 0, stream>>>(bz, bpi, bpo, B1v, L1);
  gather_feats<<<dim3(1024), dim3(256), 0, stream>>>(sparse, tables, Xb, S);
  gemm_l1     <<<dim3(256),  dim3(256), 0, stream>>>(Xb, WBb, S, L1);
  mlp_fused   <<<dim3(256),  dim3(256), 0, stream>>>(L1, dense, W1b, W2b, b1, b2, W3, b3, out);
}

// Round 4
// 70.421 us; speedup vs baseline: 7.6133x; 1.3297x over previous
//
#include <hip/hip_runtime.h>
#include <hip/hip_bf16.h>

#define B_    4096
#define F_    32
#define V_    50000
#define E_    64
#define D1_   256
#define DD_   16
#define L2N_  128
#define KX    3072      // stored X width (emb 2048 | inner 1024)
#define KTOT  7168

typedef __bf16 bf16x8 __attribute__((ext_vector_type(8)));
typedef float  f32x4  __attribute__((ext_vector_type(4)));

typedef __attribute__((address_space(1))) const void gvoid;
typedef __attribute__((address_space(3))) void svoid;

__device__ __forceinline__ ushort f2b(float f){
  __bf16 h = (__bf16)f; return __builtin_bit_cast(ushort, h);
}
__device__ __forceinline__ float b2f(ushort u){
  return __uint_as_float(((uint)u) << 16);
}
__device__ __forceinline__ void gload16(const void* g, void* l){
  __builtin_amdgcn_global_load_lds((gvoid*)g, (svoid*)l, 16, 0, 0);
}

// ============ K0: prep (blocks 0..639) + gather (blocks 640..1663) ============
// prep:   0..255  WBb[n][0:7168] = bf16 concat(Wz[n],Wpi[n],Wpo[n])
//       256..511  W1b[n][0:288]  = bf16 W1[k][n], zero-pad k>=272
//       512..639  W2b[n][0:256]  = bf16 W2[k][n]
// gather: 1 wave = 1 sample; emb->Xb bf16, s->Sb bf16, gram via MFMA -> Xb
__global__ __launch_bounds__(256) void prep_gather(
    const float* __restrict__ Wz, const float* __restrict__ Wpi,
    const float* __restrict__ Wpo, const float* __restrict__ W1,
    const float* __restrict__ W2,
    const int* __restrict__ sparse, const float* __restrict__ tables,
    ushort* __restrict__ WBb, ushort* __restrict__ W1b, ushort* __restrict__ W2b,
    ushort* __restrict__ Xb, ushort* __restrict__ Sb) {
  int bid = blockIdx.x, t = threadIdx.x;
  if (bid < 640) {
    if (bid < 256) {
      int n = bid;
#pragma unroll
      for (int j = 0; j < 7; ++j) {
        int k4 = (j * 256 + t) * 4;
        float4 v;
        if (k4 < 2048)      v = *(const float4*)&Wz [(size_t)n * 2048 + k4];
        else if (k4 < 3072) v = *(const float4*)&Wpi[(size_t)n * 1024 + (k4 - 2048)];
        else                v = *(const float4*)&Wpo[(size_t)n * 4096 + (k4 - 3072)];
        ushort4 o = make_ushort4(f2b(v.x), f2b(v.y), f2b(v.z), f2b(v.w));
        *(ushort4*)&WBb[(size_t)n * KTOT + k4] = o;
      }
    } else if (bid < 512) {
      int n = bid - 256;
      float v0 = (t < 272) ? W1[(size_t)t * 256 + n] : 0.f;
      W1b[(size_t)n * 288 + t] = f2b(v0);
      if (t < 32) {
        int k2 = 256 + t;
        float v1 = (k2 < 272) ? W1[(size_t)k2 * 256 + n] : 0.f;
        W1b[(size_t)n * 288 + k2] = f2b(v1);
      }
    } else {
      int n = bid - 512;
      W2b[(size_t)n * 256 + t] = f2b(W2[(size_t)t * 128 + n]);
    }
    return;
  }

  // ---------------- gather ----------------
  int w = t >> 6, l = t & 63;
  int b = (bid - 640) * 4 + w;
  int fr = l & 15, q = l >> 4;

  int i0 = sparse[b * F_ + fr];
  int i1 = sparse[b * F_ + 16 + fr];
  const float* r0 = tables + ((size_t)fr * V_ + i0) * 64;
  const float* r1 = tables + ((size_t)(16 + fr) * V_ + i1) * 64;

  float4 v[2][2][2];
#pragma unroll
  for (int ks = 0; ks < 2; ++ks) {
    v[0][ks][0] = *(const float4*)(r0 + ks * 32 + q * 8);
    v[0][ks][1] = *(const float4*)(r0 + ks * 32 + q * 8 + 4);
    v[1][ks][0] = *(const float4*)(r1 + ks * 32 + q * 8);
    v[1][ks][1] = *(const float4*)(r1 + ks * 32 + q * 8 + 4);
  }

  bf16x8 fg[2][2];
#pragma unroll
  for (int rh = 0; rh < 2; ++rh)
#pragma unroll
    for (int ks = 0; ks < 2; ++ks) {
      bf16x8 a;
      a[0] = (__bf16)v[rh][ks][0].x; a[1] = (__bf16)v[rh][ks][0].y;
      a[2] = (__bf16)v[rh][ks][0].z; a[3] = (__bf16)v[rh][ks][0].w;
      a[4] = (__bf16)v[rh][ks][1].x; a[5] = (__bf16)v[rh][ks][1].y;
      a[6] = (__bf16)v[rh][ks][1].z; a[7] = (__bf16)v[rh][ks][1].w;
      fg[rh][ks] = a;
      *(bf16x8*)&Xb[(size_t)b * KX + (rh * 16 + fr) * 64 + ks * 32 + q * 8] = a;
    }

  // s = column sums (fp32 shuffle-reduce), stored bf16
  float sv[2][8];
#pragma unroll
  for (int ks = 0; ks < 2; ++ks) {
    sv[ks][0] = v[0][ks][0].x + v[1][ks][0].x; sv[ks][1] = v[0][ks][0].y + v[1][ks][0].y;
    sv[ks][2] = v[0][ks][0].z + v[1][ks][0].z; sv[ks][3] = v[0][ks][0].w + v[1][ks][0].w;
    sv[ks][4] = v[0][ks][1].x + v[1][ks][1].x; sv[ks][5] = v[0][ks][1].y + v[1][ks][1].y;
    sv[ks][6] = v[0][ks][1].z + v[1][ks][1].z; sv[ks][7] = v[0][ks][1].w + v[1][ks][1].w;
  }
#pragma unroll
  for (int m = 1; m < 16; m <<= 1)
#pragma unroll
    for (int ks = 0; ks < 2; ++ks)
#pragma unroll
      for (int j = 0; j < 8; ++j)
        sv[ks][j] += __shfl_xor(sv[ks][j], m, 64);
  if (fr == 0) {
#pragma unroll
    for (int ks = 0; ks < 2; ++ks) {
      ushort4 o0 = make_ushort4(f2b(sv[ks][0]), f2b(sv[ks][1]), f2b(sv[ks][2]), f2b(sv[ks][3]));
      ushort4 o1 = make_ushort4(f2b(sv[ks][4]), f2b(sv[ks][5]), f2b(sv[ks][6]), f2b(sv[ks][7]));
      *(ushort4*)&Sb[(size_t)b * 64 + ks * 32 + q * 8]     = o0;
      *(ushort4*)&Sb[(size_t)b * 64 + ks * 32 + q * 8 + 4] = o1;
    }
  }

  // gram via MFMA (B-frag == A-frag)
  f32x4 g[2][2] = {};
#pragma unroll
  for (int ks = 0; ks < 2; ++ks)
#pragma unroll
    for (int ri = 0; ri < 2; ++ri)
#pragma unroll
      for (int rj = 0; rj < 2; ++rj)
        g[ri][rj] = __builtin_amdgcn_mfma_f32_16x16x32_bf16(
            fg[ri][ks], fg[rj][ks], g[ri][rj], 0, 0, 0);

#pragma unroll
  for (int ri = 0; ri < 2; ++ri)
#pragma unroll
    for (int rj = 0; rj < 2; ++rj)
#pragma unroll
      for (int r = 0; r < 4; ++r) {
        int rowi = ri * 16 + q * 4 + r;
        int colj = rj * 16 + fr;
        Xb[(size_t)b * KX + 2048 + rowi * 32 + colj] = f2b(g[ri][rj][r]);
      }
}

// ============ K1: split-K MFMA GEMM -> 4 partial buffers ============
// grid 256 = 32 mT x 2 nT x 4 kc. BM=BN=128, 4 waves of 64x64.
// XCD-chunked: each XCD owns one (kc,nT) -> 448 KB B-panel L2-resident.
#define BMg 128
#define BNg 128
__global__ __launch_bounds__(256, 1) void gemm_l1(
    const ushort* __restrict__ Xb, const ushort* __restrict__ WBb,
    const ushort* __restrict__ Sb, float* __restrict__ Lp) {
  __shared__ __align__(16) ushort As[2][BMg * 64];   // 32 KB
  __shared__ __align__(16) ushort Bs[2][BNg * 64];   // 32 KB
  __shared__ __align__(16) ushort Ssb[BMg * 72];     // 18 KB bf16 s rows (pad 72)

  int bid = blockIdx.x;
  int lg  = (bid & 7) * 32 + (bid >> 3);
  int kc  = lg >> 6;          // 0..3
  int nT  = (lg >> 5) & 1;    // 0..1
  int mT  = lg & 31;          // 0..31
  int bRow = mT * BMg, n0 = nT * BNg;

  int tid = threadIdx.x, w = tid >> 6, l = tid & 63;
  int wm = (w >> 1) * 64, wn = (w & 1) * 64;

  // ---- stage Ssb (bf16 s rows for 128 batch rows)
#pragma unroll
  for (int p = 0; p < 4; ++p) {
    int idx = p * 2048 + tid * 8;
    int row = idx >> 6, c = idx & 63;
    *(uint4*)&Ssb[row * 72 + c] = *(const uint4*)&Sb[(size_t)bRow * 64 + idx];
  }

  // ---- per-lane fp32 s values for outer-synthesis (static indexing)
  float sregf[4][16];
#pragma unroll
  for (int mi = 0; mi < 4; ++mi) {
    const ushort* base = Sb + (size_t)(bRow + wm + mi * 16 + (l & 15)) * 64 + (l >> 4) * 8;
    ushort4 a0 = *(const ushort4*)(base);
    ushort4 a1 = *(const ushort4*)(base + 4);
    ushort4 b0 = *(const ushort4*)(base + 32);
    ushort4 b1 = *(const ushort4*)(base + 36);
    sregf[mi][0] = b2f(a0.x); sregf[mi][1] = b2f(a0.y); sregf[mi][2] = b2f(a0.z); sregf[mi][3] = b2f(a0.w);
    sregf[mi][4] = b2f(a1.x); sregf[mi][5] = b2f(a1.y); sregf[mi][6] = b2f(a1.z); sregf[mi][7] = b2f(a1.w);
    sregf[mi][8]  = b2f(b0.x); sregf[mi][9]  = b2f(b0.y); sregf[mi][10] = b2f(b0.z); sregf[mi][11] = b2f(b0.w);
    sregf[mi][12] = b2f(b1.x); sregf[mi][13] = b2f(b1.y); sregf[mi][14] = b2f(b1.z); sregf[mi][15] = b2f(b1.w);
  }

  int r8 = l >> 3;
  int sg = ((l & 7) ^ r8) * 8;   // inverse-swizzled source slot (16B granules)

  auto stageA = [&](int bI, int kt) {   // 128 rows: wave w covers w*32 + c*8 + r8
    const ushort* src = Xb + (size_t)(bRow + w * 32 + r8) * KX + kt * 64 + sg;
#pragma unroll
    for (int c = 0; c < 4; ++c)
      gload16(src + (size_t)(c * 8) * KX, &As[bI][(w * 32 + c * 8) * 64]);
  };
  auto stageB = [&](int bI, int kt) {
    const ushort* src = WBb + (size_t)(n0 + w * 32 + r8) * KTOT + kt * 64 + sg;
#pragma unroll
    for (int c = 0; c < 4; ++c)
      gload16(src + (size_t)(c * 8) * KTOT, &Bs[bI][(w * 32 + c * 8) * 64]);
  };

  f32x4 acc[4][4] = {};
  bf16x8 af[4][2], bf[4][2];
  int buf = 0;

  // ================= X phase: kts [kc*12, kc*12+12) =================
  int kt0 = kc * 12;
  stageA(0, kt0); stageB(0, kt0);
  __syncthreads();
  for (int t = 0; t < 12; ++t) {
    if (t + 1 < 12) { stageA(buf ^ 1, kt0 + t + 1); stageB(buf ^ 1, kt0 + t + 1); }
#pragma unroll
    for (int mi = 0; mi < 4; ++mi) {
      int row = wm + mi * 16 + (l & 15);
#pragma unroll
      for (int ks = 0; ks < 2; ++ks) {
        int slot = (ks * 4 + (l >> 4)) ^ (row & 7);
        af[mi][ks] = *(const bf16x8*)&As[buf][row * 64 + slot * 8];
      }
    }
#pragma unroll
    for (int ni = 0; ni < 4; ++ni) {
      int col = wn + ni * 16 + (l & 15);
#pragma unroll
      for (int ks = 0; ks < 2; ++ks) {
        int slot = (ks * 4 + (l >> 4)) ^ (col & 7);
        bf[ni][ks] = *(const bf16x8*)&Bs[buf][col * 64 + slot * 8];
      }
    }
#pragma unroll
    for (int ks = 0; ks < 2; ++ks)
#pragma unroll
      for (int mi = 0; mi < 4; ++mi)
#pragma unroll
        for (int ni = 0; ni < 4; ++ni)
          acc[mi][ni] = __builtin_amdgcn_mfma_f32_16x16x32_bf16(
              af[mi][ks], bf[ni][ks], acc[mi][ni], 0, 0, 0);
    __syncthreads();
    buf ^= 1;
  }

  // ================= outer phase: i in [kc*16, kc*16+16) =============
  int i0 = kc * 16;
  stageB(buf, 48 + i0);
  __syncthreads();
  for (int t = 0; t < 16; ++t) {
    if (t + 1 < 16) stageB(buf ^ 1, 48 + i0 + t + 1);
    int i = i0 + t;
#pragma unroll
    for (int mi = 0; mi < 4; ++mi) {
      int row = wm + mi * 16 + (l & 15);
      float si = b2f(Ssb[row * 72 + i]);
#pragma unroll
      for (int ks = 0; ks < 2; ++ks) {
        bf16x8 a;
#pragma unroll
        for (int j = 0; j < 8; ++j)
          a[j] = (__bf16)(si * sregf[mi][ks * 8 + j]);
        af[mi][ks] = a;
      }
    }
#pragma unroll
    for (int ni = 0; ni < 4; ++ni) {
      int col = wn + ni * 16 + (l & 15);
#pragma unroll
      for (int ks = 0; ks < 2; ++ks) {
        int slot = (ks * 4 + (l >> 4)) ^ (col & 7);
        bf[ni][ks] = *(const bf16x8*)&Bs[buf][col * 64 + slot * 8];
      }
    }
#pragma unroll
    for (int ks = 0; ks < 2; ++ks)
#pragma unroll
      for (int mi = 0; mi < 4; ++mi)
#pragma unroll
        for (int ni = 0; ni < 4; ++ni)
          acc[mi][ni] = __builtin_amdgcn_mfma_f32_16x16x32_bf16(
              af[mi][ks], bf[ni][ks], acc[mi][ni], 0, 0, 0);
    __syncthreads();
    buf ^= 1;
  }

  // ---- epilogue: plain stores to partial buffer kc
  float* Lpk = Lp + (size_t)kc * (B_ * D1_);
#pragma unroll
  for (int mi = 0; mi < 4; ++mi) {
    int row0 = bRow + wm + mi * 16 + (l >> 4) * 4;
#pragma unroll
    for (int ni = 0; ni < 4; ++ni) {
      int col = n0 + wn + ni * 16 + (l & 15);
#pragma unroll
      for (int r = 0; r < 4; ++r)
        Lpk[(size_t)(row0 + r) * D1_ + col] = acc[mi][ni][r];
    }
  }
}

// ============ K2: fused MLP (sum partials + bias, layer1+layer2+head) ======
__global__ __launch_bounds__(256) void mlp_fused(
    const float* __restrict__ Lp, const float* __restrict__ dense,
    const ushort* __restrict__ W1b, const ushort* __restrict__ W2b,
    const float* __restrict__ bz, const float* __restrict__ bpi,
    const float* __restrict__ bpo, const float* __restrict__ B1v,
    const float* __restrict__ b1, const float* __restrict__ b2,
    const float* __restrict__ W3, const float* __restrict__ b3,
    float* __restrict__ out) {
  __shared__ ushort hs[16 * 264];
  __shared__ ushort h2s[16 * 136];
  __shared__ float bvs[256];
  int b0 = blockIdx.x * 16;
  int tid = threadIdx.x, w = tid >> 6, l = tid & 63;
  int row = l & 15, q = l >> 4;
  int wn = w * 64;

  bvs[tid] = bz[tid] + bpi[tid] + bpo[tid] + B1v[tid];
  __syncthreads();

  // ---- layer 1: [L1|dense|0pad] (K=288) @ W1b^T -> 256 cols
  f32x4 acc1[4] = {};
  const float* L0 = Lp;
  const float* L1p = Lp + (size_t)B_ * D1_;
  const float* L2p = Lp + (size_t)2 * B_ * D1_;
  const float* L3p = Lp + (size_t)3 * B_ * D1_;
  for (int kt = 0; kt < 9; ++kt) {
    int k0 = kt * 32 + q * 8;
    bf16x8 afr;
    if (kt < 8) {
      size_t base = (size_t)(b0 + row) * D1_ + k0;
      float4 s0 = *(const float4*)&L0[base];
      float4 s1 = *(const float4*)&L0[base + 4];
      float4 u;
      u = *(const float4*)&L1p[base];     s0.x+=u.x; s0.y+=u.y; s0.z+=u.z; s0.w+=u.w;
      u = *(const float4*)&L1p[base + 4]; s1.x+=u.x; s1.y+=u.y; s1.z+=u.z; s1.w+=u.w;
      u = *(const float4*)&L2p[base];     s0.x+=u.x; s0.y+=u.y; s0.z+=u.z; s0.w+=u.w;
      u = *(const float4*)&L2p[base + 4]; s1.x+=u.x; s1.y+=u.y; s1.z+=u.z; s1.w+=u.w;
      u = *(const float4*)&L3p[base];     s0.x+=u.x; s0.y+=u.y; s0.z+=u.z; s0.w+=u.w;
      u = *(const float4*)&L3p[base + 4]; s1.x+=u.x; s1.y+=u.y; s1.z+=u.z; s1.w+=u.w;
      float4 bv0 = *(const float4*)&bvs[k0];
      float4 bv1 = *(const float4*)&bvs[k0 + 4];
      afr[0] = (__bf16)(s0.x + bv0.x); afr[1] = (__bf16)(s0.y + bv0.y);
      afr[2] = (__bf16)(s0.z + bv0.z); afr[3] = (__bf16)(s0.w + bv0.w);
      afr[4] = (__bf16)(s1.x + bv1.x); afr[5] = (__bf16)(s1.y + bv1.y);
      afr[6] = (__bf16)(s1.z + bv1.z); afr[7] = (__bf16)(s1.w + bv1.w);
    } else if (q < 2) {
      float4 u0 = *(const float4*)&dense[(size_t)(b0 + row) * DD_ + q * 8];
      float4 u1 = *(const float4*)&dense[(size_t)(b0 + row) * DD_ + q * 8 + 4];
      afr[0] = (__bf16)u0.x; afr[1] = (__bf16)u0.y; afr[2] = (__bf16)u0.z; afr[3] = (__bf16)u0.w;
      afr[4] = (__bf16)u1.x; afr[5] = (__bf16)u1.y; afr[6] = (__bf16)u1.z; afr[7] = (__bf16)u1.w;
    } else {
      afr = (bf16x8)(__bf16)0.f;
    }
#pragma unroll
    for (int ni = 0; ni < 4; ++ni) {
      bf16x8 bfr = *(const bf16x8*)&W1b[(size_t)(wn + ni * 16 + row) * 288 + k0];
      acc1[ni] = __builtin_amdgcn_mfma_f32_16x16x32_bf16(afr, bfr, acc1[ni], 0, 0, 0);
    }
  }
#pragma unroll
  for (int ni = 0; ni < 4; ++ni) {
    int col = wn + ni * 16 + row;
    float bias = b1[col];
#pragma unroll
    for (int r = 0; r < 4; ++r)
      hs[(q * 4 + r) * 264 + col] = f2b(tanhf(acc1[ni][r] + bias));
  }
  __syncthreads();

  // ---- layer 2: h (K=256) @ W2b^T -> 128 cols
  int wn2 = w * 32;
  f32x4 acc2[2] = {};
  for (int kt = 0; kt < 8; ++kt) {
    int k0 = kt * 32 + q * 8;
    bf16x8 afr = *(const bf16x8*)&hs[row * 264 + k0];
#pragma unroll
    for (int ni = 0; ni < 2; ++ni) {
      bf16x8 bfr = *(const bf16x8*)&W2b[(size_t)(wn2 + ni * 16 + row) * 256 + k0];
      acc2[ni] = __builtin_amdgcn_mfma_f32_16x16x32_bf16(afr, bfr, acc2[ni], 0, 0, 0);
    }
  }
#pragma unroll
  for (int ni = 0; ni < 2; ++ni) {
    int col = wn2 + ni * 16 + row;
    float bias = b2[col];
#pragma unroll
    for (int r = 0; r < 4; ++r)
      h2s[(q * 4 + r) * 136 + col] = f2b(tanhf(acc2[ni][r] + bias));
  }
  __syncthreads();

  // ---- head: out = h2 @ W3 + b3 (wave 0)
  if (w == 0) {
    int rr = l >> 2, g = l & 3;
    float sum = 0.f;
#pragma unroll
    for (int jj = 0; jj < 32; ++jj) {
      int j = g * 32 + jj;
      sum += b2f(h2s[rr * 136 + j]) * W3[j];
    }
    sum += __shfl_xor(sum, 1, 64);
    sum += __shfl_xor(sum, 2, 64);
    if (g == 0) out[b0 + rr] = sum + b3[0];
  }
}

extern "C" void kernel_launch(void* const* d_in, const int* in_sizes, int n_in,
                              void* d_out, int out_size, void* d_ws, size_t ws_size,
                              hipStream_t stream) {
  const int*   sparse = (const int*)  d_in[0];
  const float* dense  = (const float*)d_in[1];
  const float* tables = (const float*)d_in[2];
  const float* Wz     = (const float*)d_in[3];
  const float* bz     = (const float*)d_in[4];
  const float* Wpi    = (const float*)d_in[5];
  const float* bpi    = (const float*)d_in[6];
  const float* Wpo    = (const float*)d_in[7];
  const float* bpo    = (const float*)d_in[8];
  const float* B1v    = (const float*)d_in[9];
  const float* W1     = (const float*)d_in[10];
  const float* b1     = (const float*)d_in[11];
  const float* W2     = (const float*)d_in[12];
  const float* b2     = (const float*)d_in[13];
  const float* W3     = (const float*)d_in[14];
  const float* b3     = (const float*)d_in[15];
  float* out = (float*)d_out;

  // ws layout (bytes), total ~44.2 MB
  char* ws = (char*)d_ws;
  ushort* Xb  = (ushort*)(ws);               // 4096*3072*2 = 25,165,824
  ushort* WBb = (ushort*)(ws + 25165824);    // 256*7168*2  =  3,670,016
  ushort* W1b = (ushort*)(ws + 28835840);    // 256*288*2   =    147,456
  ushort* W2b = (ushort*)(ws + 28983296);    // 128*256*2   =     65,536
  ushort* Sb  = (ushort*)(ws + 29048832);    // 4096*64*2   =    524,288
  float*  Lp  = (float*) (ws + 29573120);    // 4*4096*256*4= 16,777,216

  prep_gather<<<dim3(1664), dim3(256), 0, stream>>>(
      Wz, Wpi, Wpo, W1, W2, sparse, tables, WBb, W1b, W2b, Xb, Sb);
  gemm_l1    <<<dim3(256),  dim3(256), 0, stream>>>(Xb, WBb, Sb, Lp);
  mlp_fused  <<<dim3(256),  dim3(256), 0, stream>>>(
      Lp, dense, W1b, W2b, bz, bpi, bpo, B1v, b1, b2, W3, b3, out);
}